// Round 1
// baseline (2262.544 us; speedup 1.0000x reference)
//
#include <hip/hip_runtime.h>
#include <hip/hip_bf16.h>
#include <math.h>

// Problem constants (fixed by the reference setup)
constexpr int B = 8;
constexpr int V = 262144;
constexpr int J = 64;
constexpr int K = 4;
constexpr int G = 2048;
constexpr int L = 8;
constexpr int E = 1835008;
constexpr float EPS = 1e-8f;

// ---------------------------------------------------------------------------
// Kernel 0: per (b,j) normalized joint quat + dual part jd = 0.5*qmul((0,t),q)
// ws layout: 8 floats per (b*J+j): [qw,qx,qy,qz, dw,dx,dy,dz]
// ---------------------------------------------------------------------------
__global__ __launch_bounds__(256) void jqd_kernel(
    const float* __restrict__ jquat, const float* __restrict__ jtrans,
    float* __restrict__ ws) {
  int i = blockIdx.x * blockDim.x + threadIdx.x;
  if (i >= B * J) return;
  float qw = jquat[i * 4 + 0];
  float qx = jquat[i * 4 + 1];
  float qy = jquat[i * 4 + 2];
  float qz = jquat[i * 4 + 3];
  float inv = 1.0f / (sqrtf(qw * qw + qx * qx + qy * qy + qz * qz) + EPS);
  qw *= inv; qx *= inv; qy *= inv; qz *= inv;
  float tx = jtrans[i * 3 + 0];
  float ty = jtrans[i * 3 + 1];
  float tz = jtrans[i * 3 + 2];
  // qmul((0,t), q): w = -t.qv ; v = qw*t + cross(t, qv)
  float dw = -0.5f * (tx * qx + ty * qy + tz * qz);
  float dx = 0.5f * (qw * tx + (ty * qz - tz * qy));
  float dy = 0.5f * (qw * ty + (tz * qx - tx * qz));
  float dz = 0.5f * (qw * tz + (tx * qy - ty * qx));
  float* o = ws + (size_t)i * 8;
  o[0] = qw; o[1] = qx; o[2] = qy; o[3] = qz;
  o[4] = dw; o[5] = dx; o[6] = dy; o[7] = dz;
}

// ---------------------------------------------------------------------------
// Kernel 1: one thread per vertex, loop over batches.
// Writes posed (out[0]) and zeros lap (out[1]).
// ---------------------------------------------------------------------------
__global__ __launch_bounds__(256) void posed_kernel(
    const float* __restrict__ tv,     // (V,3)
    const float* __restrict__ sw_in,  // (V,K)
    const float* __restrict__ npos,   // (G,3)
    const float* __restrict__ nquat,  // (B,G,4)
    const float* __restrict__ ntrans, // (B,G,3)
    const float* __restrict__ lw_in,  // (V,L)
    const int* __restrict__ sidx,     // (V,K)
    const int* __restrict__ lidx,     // (V,L)
    const float* __restrict__ jqd,    // (B*J,8)
    float* __restrict__ out) {        // (2,B,V,3)
  int v = blockIdx.x * blockDim.x + threadIdx.x;
  if (v >= V) return;

  // ---- per-vertex loads (once, not per batch) ----
  float px = tv[(size_t)v * 3 + 0];
  float py = tv[(size_t)v * 3 + 1];
  float pz = tv[(size_t)v * 3 + 2];

  int4 si = *reinterpret_cast<const int4*>(sidx + (size_t)v * 4);
  float4 swv = *reinterpret_cast<const float4*>(sw_in + (size_t)v * 4);
  int4 li0 = *reinterpret_cast<const int4*>(lidx + (size_t)v * 8);
  int4 li1 = *reinterpret_cast<const int4*>(lidx + (size_t)v * 8 + 4);
  float4 lw0 = *reinterpret_cast<const float4*>(lw_in + (size_t)v * 8);
  float4 lw1 = *reinterpret_cast<const float4*>(lw_in + (size_t)v * 8 + 4);

  float ssum = swv.x + swv.y + swv.z + swv.w + EPS;
  float sinv = 1.0f / ssum;
  float swn[K] = {swv.x * sinv, swv.y * sinv, swv.z * sinv, swv.w * sinv};
  int sj[K] = {si.x, si.y, si.z, si.w};

  float lsum = lw0.x + lw0.y + lw0.z + lw0.w + lw1.x + lw1.y + lw1.z + lw1.w + EPS;
  float linv = 1.0f / lsum;
  float lwn[L] = {lw0.x * linv, lw0.y * linv, lw0.z * linv, lw0.w * linv,
                  lw1.x * linv, lw1.y * linv, lw1.z * linv, lw1.w * linv};
  int gi[L] = {li0.x, li0.y, li0.z, li0.w, li1.x, li1.y, li1.z, li1.w};

  // batch-invariant: local = p - gp, base = sum lw*gp
  float lx[L], ly[L], lz[L];
  float bx = 0.f, by = 0.f, bz = 0.f;
#pragma unroll
  for (int l = 0; l < L; ++l) {
    float gx = npos[(size_t)gi[l] * 3 + 0];
    float gy = npos[(size_t)gi[l] * 3 + 1];
    float gz = npos[(size_t)gi[l] * 3 + 2];
    lx[l] = px - gx; ly[l] = py - gy; lz[l] = pz - gz;
    bx += lwn[l] * gx; by += lwn[l] * gy; bz += lwn[l] * gz;
  }

  constexpr size_t LAPOFF = (size_t)B * V * 3;

  for (int b = 0; b < B; ++b) {
    const float* nq_b = nquat + (size_t)b * G * 4;
    const float* nt_b = ntrans + (size_t)b * G * 3;

    // ---- v_eg = sum_l lw * (qrot(nq, local) + gp + nt) ----
    float ex = bx, ey = by, ez = bz;
#pragma unroll
    for (int l = 0; l < L; ++l) {
      float4 q = *reinterpret_cast<const float4*>(nq_b + (size_t)gi[l] * 4);
      float qw = q.x, qx = q.y, qy = q.z, qz = q.w;
      float inv = 1.0f / (sqrtf(qw * qw + qx * qx + qy * qy + qz * qz) + EPS);
      qw *= inv; qx *= inv; qy *= inv; qz *= inv;
      float ux = lx[l], uy = ly[l], uz = lz[l];
      // c = cross(qv,u) + qw*u
      float cx = qy * uz - qz * uy + qw * ux;
      float cy = qz * ux - qx * uz + qw * uy;
      float cz = qx * uy - qy * ux + qw * uz;
      // r = u + 2*cross(qv,c)
      float rx = ux + 2.0f * (qy * cz - qz * cy);
      float ry = uy + 2.0f * (qz * cx - qx * cz);
      float rz = uz + 2.0f * (qx * cy - qy * cx);
      float ntx = nt_b[(size_t)gi[l] * 3 + 0];
      float nty = nt_b[(size_t)gi[l] * 3 + 1];
      float ntz = nt_b[(size_t)gi[l] * 3 + 2];
      ex += lwn[l] * (rx + ntx);
      ey += lwn[l] * (ry + nty);
      ez += lwn[l] * (rz + ntz);
    }

    // ---- joint dual-quat blend ----
    float rbw = 0.f, rbx = 0.f, rby = 0.f, rbz = 0.f;
    float dbw = 0.f, dbx = 0.f, dby = 0.f, dbz = 0.f;
    float r0w = 0.f, r0x = 0.f, r0y = 0.f, r0z = 0.f;
#pragma unroll
    for (int k = 0; k < K; ++k) {
      const float* eptr = jqd + ((size_t)b * J + sj[k]) * 8;
      float4 qf = *reinterpret_cast<const float4*>(eptr);
      float4 df = *reinterpret_cast<const float4*>(eptr + 4);
      float qw = qf.x, qx = qf.y, qy = qf.z, qz = qf.w;
      if (k == 0) { r0w = qw; r0x = qx; r0y = qy; r0z = qz; }
      float dotr = qw * r0w + qx * r0x + qy * r0y + qz * r0z;
      float s = (dotr >= 0.0f) ? swn[k] : -swn[k];
      rbw += s * qw; rbx += s * qx; rby += s * qy; rbz += s * qz;
      dbw += s * df.x; dbx += s * df.y; dby += s * df.z; dbz += s * df.w;
    }
    float ninv = 1.0f / (sqrtf(rbw * rbw + rbx * rbx + rby * rby + rbz * rbz) + EPS);
    rbw *= ninv; rbx *= ninv; rby *= ninv; rbz *= ninv;
    dbw *= ninv; dbx *= ninv; dby *= ninv; dbz *= ninv;

    // trans = 2*(rw*dv - dw*rv + cross(rv,dv))
    float txx = 2.0f * (rbw * dbx - dbw * rbx + (rby * dbz - rbz * dby));
    float tyy = 2.0f * (rbw * dby - dbw * rby + (rbz * dbx - rbx * dbz));
    float tzz = 2.0f * (rbw * dbz - dbw * rbz + (rbx * dby - rby * dbx));

    // posed = qrot(rb, v_eg) + trans
    float cx = rby * ez - rbz * ey + rbw * ex;
    float cy = rbz * ex - rbx * ez + rbw * ey;
    float cz = rbx * ey - rby * ex + rbw * ez;
    float ox = ex + 2.0f * (rby * cz - rbz * cy) + txx;
    float oy = ey + 2.0f * (rbz * cx - rbx * cz) + tyy;
    float oz = ez + 2.0f * (rbx * cy - rby * cx) + tzz;

    size_t o = ((size_t)b * V + v) * 3;
    out[o + 0] = ox; out[o + 1] = oy; out[o + 2] = oz;
    // zero the lap half (d_out is poisoned; must be zeroed every launch)
    out[LAPOFF + o + 0] = 0.f;
    out[LAPOFF + o + 1] = 0.f;
    out[LAPOFF + o + 2] = 0.f;
  }
}

// ---------------------------------------------------------------------------
// Kernel 2: one thread per edge, loop over batches; scatter-add into lap.
// ---------------------------------------------------------------------------
__global__ __launch_bounds__(256) void lap_kernel(
    const float* __restrict__ lapw, const int* __restrict__ st,
    const int* __restrict__ ed, const float* __restrict__ posed,
    float* __restrict__ lap) {
  int e = blockIdx.x * blockDim.x + threadIdx.x;
  if (e >= E) return;
  float w = lapw[e];
  int s = st[e];
  int d = ed[e];
#pragma unroll
  for (int b = 0; b < B; ++b) {
    size_t pb = ((size_t)b * V + d) * 3;
    size_t ob = ((size_t)b * V + s) * 3;
    atomicAdd(&lap[ob + 0], w * posed[pb + 0]);
    atomicAdd(&lap[ob + 1], w * posed[pb + 1]);
    atomicAdd(&lap[ob + 2], w * posed[pb + 2]);
  }
}

extern "C" void kernel_launch(void* const* d_in, const int* in_sizes, int n_in,
                              void* d_out, int out_size, void* d_ws, size_t ws_size,
                              hipStream_t stream) {
  const float* tv    = (const float*)d_in[0];
  const float* jquat = (const float*)d_in[1];
  const float* jtran = (const float*)d_in[2];
  const float* sw    = (const float*)d_in[3];
  const float* npos  = (const float*)d_in[4];
  const float* nquat = (const float*)d_in[5];
  const float* ntran = (const float*)d_in[6];
  const float* lw    = (const float*)d_in[7];
  const float* lapw  = (const float*)d_in[8];
  const int*   sidx  = (const int*)d_in[9];
  const int*   lidx  = (const int*)d_in[10];
  const int*   lst   = (const int*)d_in[11];
  const int*   led   = (const int*)d_in[12];
  float* out = (float*)d_out;
  float* jqd = (float*)d_ws;  // B*J*8 floats = 16 KB

  jqd_kernel<<<(B * J + 255) / 256, 256, 0, stream>>>(jquat, jtran, jqd);
  posed_kernel<<<V / 256, 256, 0, stream>>>(tv, sw, npos, nquat, ntran, lw,
                                            sidx, lidx, jqd, out);
  lap_kernel<<<(E + 255) / 256, 256, 0, stream>>>(
      lapw, lst, led, out, out + (size_t)B * V * 3);
}

// Round 2
// 572.705 us; speedup vs baseline: 3.9506x; 3.9506x over previous
//
#include <hip/hip_runtime.h>
#include <hip/hip_bf16.h>
#include <math.h>

// Problem constants (fixed by the reference setup)
constexpr int B = 8;
constexpr int V = 262144;
constexpr int J = 64;
constexpr int K = 4;
constexpr int G = 2048;
constexpr int L = 8;
constexpr int E = 1835008;
constexpr float EPS = 1e-8f;
constexpr int NBLK = V / 256;  // 1024 scan blocks

// ---------------------------------------------------------------------------
// Kernel 0: per (b,j) normalized joint quat + dual part jd = 0.5*qmul((0,t),q)
// ---------------------------------------------------------------------------
__global__ __launch_bounds__(256) void jqd_kernel(
    const float* __restrict__ jquat, const float* __restrict__ jtrans,
    float* __restrict__ ws) {
  int i = blockIdx.x * blockDim.x + threadIdx.x;
  if (i >= B * J) return;
  float qw = jquat[i * 4 + 0];
  float qx = jquat[i * 4 + 1];
  float qy = jquat[i * 4 + 2];
  float qz = jquat[i * 4 + 3];
  float inv = 1.0f / (sqrtf(qw * qw + qx * qx + qy * qy + qz * qz) + EPS);
  qw *= inv; qx *= inv; qy *= inv; qz *= inv;
  float tx = jtrans[i * 3 + 0];
  float ty = jtrans[i * 3 + 1];
  float tz = jtrans[i * 3 + 2];
  float dw = -0.5f * (tx * qx + ty * qy + tz * qz);
  float dx = 0.5f * (qw * tx + (ty * qz - tz * qy));
  float dy = 0.5f * (qw * ty + (tz * qx - tx * qz));
  float dz = 0.5f * (qw * tz + (tx * qy - ty * qx));
  float* o = ws + (size_t)i * 8;
  o[0] = qw; o[1] = qx; o[2] = qy; o[3] = qz;
  o[4] = dw; o[5] = dx; o[6] = dy; o[7] = dz;
}

// ---------------------------------------------------------------------------
// Kernel 1: one thread per vertex, loop over batches. Writes posed (out[0]).
// zeroLap!=0 only in the (atomic) fallback path.
// ---------------------------------------------------------------------------
__global__ __launch_bounds__(256) void posed_kernel(
    const float* __restrict__ tv, const float* __restrict__ sw_in,
    const float* __restrict__ npos, const float* __restrict__ nquat,
    const float* __restrict__ ntrans, const float* __restrict__ lw_in,
    const int* __restrict__ sidx, const int* __restrict__ lidx,
    const float* __restrict__ jqd, float* __restrict__ out, int zeroLap) {
  int v = blockIdx.x * blockDim.x + threadIdx.x;
  if (v >= V) return;

  float px = tv[(size_t)v * 3 + 0];
  float py = tv[(size_t)v * 3 + 1];
  float pz = tv[(size_t)v * 3 + 2];

  int4 si = *reinterpret_cast<const int4*>(sidx + (size_t)v * 4);
  float4 swv = *reinterpret_cast<const float4*>(sw_in + (size_t)v * 4);
  int4 li0 = *reinterpret_cast<const int4*>(lidx + (size_t)v * 8);
  int4 li1 = *reinterpret_cast<const int4*>(lidx + (size_t)v * 8 + 4);
  float4 lw0 = *reinterpret_cast<const float4*>(lw_in + (size_t)v * 8);
  float4 lw1 = *reinterpret_cast<const float4*>(lw_in + (size_t)v * 8 + 4);

  float sinv = 1.0f / (swv.x + swv.y + swv.z + swv.w + EPS);
  float swn[K] = {swv.x * sinv, swv.y * sinv, swv.z * sinv, swv.w * sinv};
  int sj[K] = {si.x, si.y, si.z, si.w};

  float linv =
      1.0f / (lw0.x + lw0.y + lw0.z + lw0.w + lw1.x + lw1.y + lw1.z + lw1.w + EPS);
  float lwn[L] = {lw0.x * linv, lw0.y * linv, lw0.z * linv, lw0.w * linv,
                  lw1.x * linv, lw1.y * linv, lw1.z * linv, lw1.w * linv};
  int gi[L] = {li0.x, li0.y, li0.z, li0.w, li1.x, li1.y, li1.z, li1.w};

  float lx[L], ly[L], lz[L];
  float bx = 0.f, by = 0.f, bz = 0.f;
#pragma unroll
  for (int l = 0; l < L; ++l) {
    float gx = npos[(size_t)gi[l] * 3 + 0];
    float gy = npos[(size_t)gi[l] * 3 + 1];
    float gz = npos[(size_t)gi[l] * 3 + 2];
    lx[l] = px - gx; ly[l] = py - gy; lz[l] = pz - gz;
    bx += lwn[l] * gx; by += lwn[l] * gy; bz += lwn[l] * gz;
  }

  constexpr size_t LAPOFF = (size_t)B * V * 3;

  for (int b = 0; b < B; ++b) {
    const float* nq_b = nquat + (size_t)b * G * 4;
    const float* nt_b = ntrans + (size_t)b * G * 3;

    float ex = bx, ey = by, ez = bz;
#pragma unroll
    for (int l = 0; l < L; ++l) {
      float4 q = *reinterpret_cast<const float4*>(nq_b + (size_t)gi[l] * 4);
      float qw = q.x, qx = q.y, qy = q.z, qz = q.w;
      float inv = 1.0f / (sqrtf(qw * qw + qx * qx + qy * qy + qz * qz) + EPS);
      qw *= inv; qx *= inv; qy *= inv; qz *= inv;
      float ux = lx[l], uy = ly[l], uz = lz[l];
      float cx = qy * uz - qz * uy + qw * ux;
      float cy = qz * ux - qx * uz + qw * uy;
      float cz = qx * uy - qy * ux + qw * uz;
      float rx = ux + 2.0f * (qy * cz - qz * cy);
      float ry = uy + 2.0f * (qz * cx - qx * cz);
      float rz = uz + 2.0f * (qx * cy - qy * cx);
      ex += lwn[l] * (rx + nt_b[(size_t)gi[l] * 3 + 0]);
      ey += lwn[l] * (ry + nt_b[(size_t)gi[l] * 3 + 1]);
      ez += lwn[l] * (rz + nt_b[(size_t)gi[l] * 3 + 2]);
    }

    float rbw = 0.f, rbx = 0.f, rby = 0.f, rbz = 0.f;
    float dbw = 0.f, dbx = 0.f, dby = 0.f, dbz = 0.f;
    float r0w = 0.f, r0x = 0.f, r0y = 0.f, r0z = 0.f;
#pragma unroll
    for (int k = 0; k < K; ++k) {
      const float* eptr = jqd + ((size_t)b * J + sj[k]) * 8;
      float4 qf = *reinterpret_cast<const float4*>(eptr);
      float4 df = *reinterpret_cast<const float4*>(eptr + 4);
      float qw = qf.x, qx = qf.y, qy = qf.z, qz = qf.w;
      if (k == 0) { r0w = qw; r0x = qx; r0y = qy; r0z = qz; }
      float dotr = qw * r0w + qx * r0x + qy * r0y + qz * r0z;
      float s = (dotr >= 0.0f) ? swn[k] : -swn[k];
      rbw += s * qw; rbx += s * qx; rby += s * qy; rbz += s * qz;
      dbw += s * df.x; dbx += s * df.y; dby += s * df.z; dbz += s * df.w;
    }
    float ninv = 1.0f / (sqrtf(rbw * rbw + rbx * rbx + rby * rby + rbz * rbz) + EPS);
    rbw *= ninv; rbx *= ninv; rby *= ninv; rbz *= ninv;
    dbw *= ninv; dbx *= ninv; dby *= ninv; dbz *= ninv;

    float txx = 2.0f * (rbw * dbx - dbw * rbx + (rby * dbz - rbz * dby));
    float tyy = 2.0f * (rbw * dby - dbw * rby + (rbz * dbx - rbx * dbz));
    float tzz = 2.0f * (rbw * dbz - dbw * rbz + (rbx * dby - rby * dbx));

    float cx = rby * ez - rbz * ey + rbw * ex;
    float cy = rbz * ex - rbx * ez + rbw * ey;
    float cz = rbx * ey - rby * ex + rbw * ez;
    float ox = ex + 2.0f * (rby * cz - rbz * cy) + txx;
    float oy = ey + 2.0f * (rbz * cx - rbx * cz) + tyy;
    float oz = ez + 2.0f * (rbx * cy - rby * cx) + tzz;

    size_t o = ((size_t)b * V + v) * 3;
    out[o + 0] = ox; out[o + 1] = oy; out[o + 2] = oz;
    if (zeroLap) {
      out[LAPOFF + o + 0] = 0.f;
      out[LAPOFF + o + 1] = 0.f;
      out[LAPOFF + o + 2] = 0.f;
    }
  }
}

// ---------------------------------------------------------------------------
// CSR build: histogram -> scan -> scatter
// ---------------------------------------------------------------------------
__global__ __launch_bounds__(256) void hist_kernel(const int* __restrict__ st,
                                                   int* __restrict__ cnt) {
  int e = blockIdx.x * blockDim.x + threadIdx.x;
  if (e < E) atomicAdd(&cnt[st[e]], 1);
}

// per-block exclusive scan of 256-elem chunks; block totals to bsum
__global__ __launch_bounds__(256) void scan1_kernel(const int* __restrict__ cnt,
                                                    int* __restrict__ excl,
                                                    int* __restrict__ bsum) {
  __shared__ int s[256];
  int t = threadIdx.x;
  int i = blockIdx.x * 256 + t;
  int x = cnt[i];
  s[t] = x;
  __syncthreads();
  for (int off = 1; off < 256; off <<= 1) {
    int val = (t >= off) ? s[t - off] : 0;
    __syncthreads();
    s[t] += val;
    __syncthreads();
  }
  excl[i] = s[t] - x;
  if (t == 255) bsum[blockIdx.x] = s[t];
}

// single-block exclusive scan of NBLK block sums
__global__ __launch_bounds__(1024) void scan2_kernel(const int* __restrict__ bsum,
                                                     int* __restrict__ boff) {
  __shared__ int s[NBLK];
  int t = threadIdx.x;
  int x = bsum[t];
  s[t] = x;
  __syncthreads();
  for (int off = 1; off < NBLK; off <<= 1) {
    int val = (t >= off) ? s[t - off] : 0;
    __syncthreads();
    s[t] += val;
    __syncthreads();
  }
  boff[t] = s[t] - x;
}

__global__ __launch_bounds__(256) void scan3_kernel(int* __restrict__ excl,
                                                    const int* __restrict__ boff,
                                                    int* __restrict__ cursor) {
  int i = blockIdx.x * 256 + threadIdx.x;
  int r = excl[i] + boff[blockIdx.x];
  excl[i] = r;
  cursor[i] = r;
  if (i == 0) excl[V] = E;
}

__global__ __launch_bounds__(256) void scatter_kernel(
    const int* __restrict__ st, const int* __restrict__ ed,
    const float* __restrict__ w, int* __restrict__ cursor,
    int* __restrict__ eD, float* __restrict__ eW) {
  int e = blockIdx.x * blockDim.x + threadIdx.x;
  if (e >= E) return;
  int pos = atomicAdd(&cursor[st[e]], 1);
  eD[pos] = ed[e];
  eW[pos] = w[e];
}

// ---------------------------------------------------------------------------
// Gather: one thread per vertex; acc[B][3] in registers; no atomics.
// ---------------------------------------------------------------------------
__global__ __launch_bounds__(256) void lap_gather_kernel(
    const int* __restrict__ rowstart, const int* __restrict__ eD,
    const float* __restrict__ eW, const float* __restrict__ posed,
    float* __restrict__ lap) {
  int v = blockIdx.x * blockDim.x + threadIdx.x;
  if (v >= V) return;
  int beg = rowstart[v];
  int end = rowstart[v + 1];
  float acc[B][3];
#pragma unroll
  for (int b = 0; b < B; ++b) { acc[b][0] = 0.f; acc[b][1] = 0.f; acc[b][2] = 0.f; }
  for (int j = beg; j < end; ++j) {
    int d = eD[j];
    float w = eW[j];
    const float* p = posed + (size_t)d * 3;
#pragma unroll
    for (int b = 0; b < B; ++b) {
      const float* pb = p + (size_t)b * V * 3;
      acc[b][0] += w * pb[0];
      acc[b][1] += w * pb[1];
      acc[b][2] += w * pb[2];
    }
  }
#pragma unroll
  for (int b = 0; b < B; ++b) {
    size_t o = ((size_t)b * V + v) * 3;
    lap[o + 0] = acc[b][0];
    lap[o + 1] = acc[b][1];
    lap[o + 2] = acc[b][2];
  }
}

// ---------------------------------------------------------------------------
// Fallback (ws too small): per-edge atomic scatter
// ---------------------------------------------------------------------------
__global__ __launch_bounds__(256) void lap_atomic_kernel(
    const float* __restrict__ lapw, const int* __restrict__ st,
    const int* __restrict__ ed, const float* __restrict__ posed,
    float* __restrict__ lap) {
  int e = blockIdx.x * blockDim.x + threadIdx.x;
  if (e >= E) return;
  float w = lapw[e];
  int s = st[e];
  int d = ed[e];
#pragma unroll
  for (int b = 0; b < B; ++b) {
    size_t pb = ((size_t)b * V + d) * 3;
    size_t ob = ((size_t)b * V + s) * 3;
    atomicAdd(&lap[ob + 0], w * posed[pb + 0]);
    atomicAdd(&lap[ob + 1], w * posed[pb + 1]);
    atomicAdd(&lap[ob + 2], w * posed[pb + 2]);
  }
}

extern "C" void kernel_launch(void* const* d_in, const int* in_sizes, int n_in,
                              void* d_out, int out_size, void* d_ws, size_t ws_size,
                              hipStream_t stream) {
  const float* tv    = (const float*)d_in[0];
  const float* jquat = (const float*)d_in[1];
  const float* jtran = (const float*)d_in[2];
  const float* sw    = (const float*)d_in[3];
  const float* npos  = (const float*)d_in[4];
  const float* nquat = (const float*)d_in[5];
  const float* ntran = (const float*)d_in[6];
  const float* lw    = (const float*)d_in[7];
  const float* lapw  = (const float*)d_in[8];
  const int*   sidx  = (const int*)d_in[9];
  const int*   lidx  = (const int*)d_in[10];
  const int*   lst   = (const int*)d_in[11];
  const int*   led   = (const int*)d_in[12];
  float* out = (float*)d_out;
  float* lap = out + (size_t)B * V * 3;

  // workspace layout
  float* jqd     = (float*)d_ws;            // 4096 floats (16 KB)
  int*   cnt     = (int*)(jqd + 4096);      // V
  int*   rowstart= cnt + V;                 // V+1
  int*   cursor  = rowstart + V + 1;        // V
  int*   bsum    = cursor + V;              // NBLK
  int*   boff    = bsum + NBLK;             // NBLK
  int*   eD      = boff + NBLK;             // E
  float* eW      = (float*)(eD + E);        // E
  size_t need = (size_t)((char*)(eW + E) - (char*)d_ws);
  bool csr = ws_size >= need;

  jqd_kernel<<<(B * J + 255) / 256, 256, 0, stream>>>(jquat, jtran, jqd);
  posed_kernel<<<V / 256, 256, 0, stream>>>(tv, sw, npos, nquat, ntran, lw,
                                            sidx, lidx, jqd, out, csr ? 0 : 1);
  if (csr) {
    hipMemsetAsync(cnt, 0, (size_t)V * sizeof(int), stream);
    hist_kernel<<<E / 256, 256, 0, stream>>>(lst, cnt);
    scan1_kernel<<<NBLK, 256, 0, stream>>>(cnt, rowstart, bsum);
    scan2_kernel<<<1, NBLK, 0, stream>>>(bsum, boff);
    scan3_kernel<<<NBLK, 256, 0, stream>>>(rowstart, boff, cursor);
    scatter_kernel<<<E / 256, 256, 0, stream>>>(lst, led, lapw, cursor, eD, eW);
    lap_gather_kernel<<<V / 256, 256, 0, stream>>>(rowstart, eD, eW, out, lap);
  } else {
    lap_atomic_kernel<<<E / 256, 256, 0, stream>>>(lapw, lst, led, out, lap);
  }
}

// Round 3
// 385.920 us; speedup vs baseline: 5.8627x; 1.4840x over previous
//
#include <hip/hip_runtime.h>
#include <hip/hip_bf16.h>
#include <math.h>

// Problem constants (fixed by the reference setup)
constexpr int B = 8;
constexpr int V = 262144;
constexpr int J = 64;
constexpr int K = 4;
constexpr int G = 2048;
constexpr int L = 8;
constexpr int E = 1835008;
constexpr float EPS = 1e-8f;
constexpr int NBLK = V / 256;  // 1024 scan blocks

// ---------------------------------------------------------------------------
// Kernel 0: per (b,j) normalized joint quat + dual part jd = 0.5*qmul((0,t),q)
// ---------------------------------------------------------------------------
__global__ __launch_bounds__(256) void jqd_kernel(
    const float* __restrict__ jquat, const float* __restrict__ jtrans,
    float* __restrict__ ws) {
  int i = blockIdx.x * blockDim.x + threadIdx.x;
  if (i >= B * J) return;
  float qw = jquat[i * 4 + 0];
  float qx = jquat[i * 4 + 1];
  float qy = jquat[i * 4 + 2];
  float qz = jquat[i * 4 + 3];
  float inv = 1.0f / (sqrtf(qw * qw + qx * qx + qy * qy + qz * qz) + EPS);
  qw *= inv; qx *= inv; qy *= inv; qz *= inv;
  float tx = jtrans[i * 3 + 0];
  float ty = jtrans[i * 3 + 1];
  float tz = jtrans[i * 3 + 2];
  float dw = -0.5f * (tx * qx + ty * qy + tz * qz);
  float dx = 0.5f * (qw * tx + (ty * qz - tz * qy));
  float dy = 0.5f * (qw * ty + (tz * qx - tx * qz));
  float dz = 0.5f * (qw * tz + (tx * qy - ty * qx));
  float* o = ws + (size_t)i * 8;
  o[0] = qw; o[1] = qx; o[2] = qy; o[3] = qz;
  o[4] = dw; o[5] = dx; o[6] = dy; o[7] = dz;
}

// ---------------------------------------------------------------------------
// Kernel 1: one thread per vertex, loop over batches. Writes posed (out[0])
// and optionally a vertex-major copy pvm[v][b][3] (24 floats / vertex).
// mode: 0 = write pvm, 1 = no pvm, 2 = no pvm + zero lap (atomic fallback)
// ---------------------------------------------------------------------------
__global__ __launch_bounds__(256) void posed_kernel(
    const float* __restrict__ tv, const float* __restrict__ sw_in,
    const float* __restrict__ npos, const float* __restrict__ nquat,
    const float* __restrict__ ntrans, const float* __restrict__ lw_in,
    const int* __restrict__ sidx, const int* __restrict__ lidx,
    const float* __restrict__ jqd, float* __restrict__ out,
    float* __restrict__ pvm, int mode) {
  int v = blockIdx.x * blockDim.x + threadIdx.x;
  if (v >= V) return;

  float px = tv[(size_t)v * 3 + 0];
  float py = tv[(size_t)v * 3 + 1];
  float pz = tv[(size_t)v * 3 + 2];

  int4 si = *reinterpret_cast<const int4*>(sidx + (size_t)v * 4);
  float4 swv = *reinterpret_cast<const float4*>(sw_in + (size_t)v * 4);
  int4 li0 = *reinterpret_cast<const int4*>(lidx + (size_t)v * 8);
  int4 li1 = *reinterpret_cast<const int4*>(lidx + (size_t)v * 8 + 4);
  float4 lw0 = *reinterpret_cast<const float4*>(lw_in + (size_t)v * 8);
  float4 lw1 = *reinterpret_cast<const float4*>(lw_in + (size_t)v * 8 + 4);

  float sinv = 1.0f / (swv.x + swv.y + swv.z + swv.w + EPS);
  float swn[K] = {swv.x * sinv, swv.y * sinv, swv.z * sinv, swv.w * sinv};
  int sj[K] = {si.x, si.y, si.z, si.w};

  float linv =
      1.0f / (lw0.x + lw0.y + lw0.z + lw0.w + lw1.x + lw1.y + lw1.z + lw1.w + EPS);
  float lwn[L] = {lw0.x * linv, lw0.y * linv, lw0.z * linv, lw0.w * linv,
                  lw1.x * linv, lw1.y * linv, lw1.z * linv, lw1.w * linv};
  int gi[L] = {li0.x, li0.y, li0.z, li0.w, li1.x, li1.y, li1.z, li1.w};

  float lx[L], ly[L], lz[L];
  float bx = 0.f, by = 0.f, bz = 0.f;
#pragma unroll
  for (int l = 0; l < L; ++l) {
    float gx = npos[(size_t)gi[l] * 3 + 0];
    float gy = npos[(size_t)gi[l] * 3 + 1];
    float gz = npos[(size_t)gi[l] * 3 + 2];
    lx[l] = px - gx; ly[l] = py - gy; lz[l] = pz - gz;
    bx += lwn[l] * gx; by += lwn[l] * gy; bz += lwn[l] * gz;
  }

  constexpr size_t LAPOFF = (size_t)B * V * 3;
  float pv[24];

  for (int b = 0; b < B; ++b) {
    const float* nq_b = nquat + (size_t)b * G * 4;
    const float* nt_b = ntrans + (size_t)b * G * 3;

    float ex = bx, ey = by, ez = bz;
#pragma unroll
    for (int l = 0; l < L; ++l) {
      float4 q = *reinterpret_cast<const float4*>(nq_b + (size_t)gi[l] * 4);
      float qw = q.x, qx = q.y, qy = q.z, qz = q.w;
      float inv = 1.0f / (sqrtf(qw * qw + qx * qx + qy * qy + qz * qz) + EPS);
      qw *= inv; qx *= inv; qy *= inv; qz *= inv;
      float ux = lx[l], uy = ly[l], uz = lz[l];
      float cx = qy * uz - qz * uy + qw * ux;
      float cy = qz * ux - qx * uz + qw * uy;
      float cz = qx * uy - qy * ux + qw * uz;
      float rx = ux + 2.0f * (qy * cz - qz * cy);
      float ry = uy + 2.0f * (qz * cx - qx * cz);
      float rz = uz + 2.0f * (qx * cy - qy * cx);
      ex += lwn[l] * (rx + nt_b[(size_t)gi[l] * 3 + 0]);
      ey += lwn[l] * (ry + nt_b[(size_t)gi[l] * 3 + 1]);
      ez += lwn[l] * (rz + nt_b[(size_t)gi[l] * 3 + 2]);
    }

    float rbw = 0.f, rbx = 0.f, rby = 0.f, rbz = 0.f;
    float dbw = 0.f, dbx = 0.f, dby = 0.f, dbz = 0.f;
    float r0w = 0.f, r0x = 0.f, r0y = 0.f, r0z = 0.f;
#pragma unroll
    for (int k = 0; k < K; ++k) {
      const float* eptr = jqd + ((size_t)b * J + sj[k]) * 8;
      float4 qf = *reinterpret_cast<const float4*>(eptr);
      float4 df = *reinterpret_cast<const float4*>(eptr + 4);
      float qw = qf.x, qx = qf.y, qy = qf.z, qz = qf.w;
      if (k == 0) { r0w = qw; r0x = qx; r0y = qy; r0z = qz; }
      float dotr = qw * r0w + qx * r0x + qy * r0y + qz * r0z;
      float s = (dotr >= 0.0f) ? swn[k] : -swn[k];
      rbw += s * qw; rbx += s * qx; rby += s * qy; rbz += s * qz;
      dbw += s * df.x; dbx += s * df.y; dby += s * df.z; dbz += s * df.w;
    }
    float ninv = 1.0f / (sqrtf(rbw * rbw + rbx * rbx + rby * rby + rbz * rbz) + EPS);
    rbw *= ninv; rbx *= ninv; rby *= ninv; rbz *= ninv;
    dbw *= ninv; dbx *= ninv; dby *= ninv; dbz *= ninv;

    float txx = 2.0f * (rbw * dbx - dbw * rbx + (rby * dbz - rbz * dby));
    float tyy = 2.0f * (rbw * dby - dbw * rby + (rbz * dbx - rbx * dbz));
    float tzz = 2.0f * (rbw * dbz - dbw * rbz + (rbx * dby - rby * dbx));

    float cx = rby * ez - rbz * ey + rbw * ex;
    float cy = rbz * ex - rbx * ez + rbw * ey;
    float cz = rbx * ey - rby * ex + rbw * ez;
    float ox = ex + 2.0f * (rby * cz - rbz * cy) + txx;
    float oy = ey + 2.0f * (rbz * cx - rbx * cz) + tyy;
    float oz = ez + 2.0f * (rbx * cy - rby * cx) + tzz;

    size_t o = ((size_t)b * V + v) * 3;
    out[o + 0] = ox; out[o + 1] = oy; out[o + 2] = oz;
    pv[b * 3 + 0] = ox; pv[b * 3 + 1] = oy; pv[b * 3 + 2] = oz;
    if (mode == 2) {
      out[LAPOFF + o + 0] = 0.f;
      out[LAPOFF + o + 1] = 0.f;
      out[LAPOFF + o + 2] = 0.f;
    }
  }

  if (mode == 0) {
    float4* dst = reinterpret_cast<float4*>(pvm + (size_t)v * 24);
#pragma unroll
    for (int q = 0; q < 6; ++q) {
      dst[q] = make_float4(pv[q * 4 + 0], pv[q * 4 + 1], pv[q * 4 + 2],
                           pv[q * 4 + 3]);
    }
  }
}

// ---------------------------------------------------------------------------
// CSR build: histogram -> scan -> scatter (packed int2 payload)
// ---------------------------------------------------------------------------
__global__ __launch_bounds__(256) void hist_kernel(const int* __restrict__ st,
                                                   int* __restrict__ cnt) {
  int e = blockIdx.x * blockDim.x + threadIdx.x;
  if (e < E) atomicAdd(&cnt[st[e]], 1);
}

__global__ __launch_bounds__(256) void scan1_kernel(const int* __restrict__ cnt,
                                                    int* __restrict__ excl,
                                                    int* __restrict__ bsum) {
  __shared__ int s[256];
  int t = threadIdx.x;
  int i = blockIdx.x * 256 + t;
  int x = cnt[i];
  s[t] = x;
  __syncthreads();
  for (int off = 1; off < 256; off <<= 1) {
    int val = (t >= off) ? s[t - off] : 0;
    __syncthreads();
    s[t] += val;
    __syncthreads();
  }
  excl[i] = s[t] - x;
  if (t == 255) bsum[blockIdx.x] = s[t];
}

__global__ __launch_bounds__(1024) void scan2_kernel(const int* __restrict__ bsum,
                                                     int* __restrict__ boff) {
  __shared__ int s[NBLK];
  int t = threadIdx.x;
  int x = bsum[t];
  s[t] = x;
  __syncthreads();
  for (int off = 1; off < NBLK; off <<= 1) {
    int val = (t >= off) ? s[t - off] : 0;
    __syncthreads();
    s[t] += val;
    __syncthreads();
  }
  boff[t] = s[t] - x;
}

__global__ __launch_bounds__(256) void scan3_kernel(int* __restrict__ excl,
                                                    const int* __restrict__ boff,
                                                    int* __restrict__ cursor) {
  int i = blockIdx.x * 256 + threadIdx.x;
  int r = excl[i] + boff[blockIdx.x];
  excl[i] = r;
  cursor[i] = r;
  if (i == 0) excl[V] = E;
}

__global__ __launch_bounds__(256) void scatter_kernel(
    const int* __restrict__ st, const int* __restrict__ ed,
    const float* __restrict__ w, int* __restrict__ cursor,
    int2* __restrict__ e2) {
  int e = blockIdx.x * blockDim.x + threadIdx.x;
  if (e >= E) return;
  int pos = atomicAdd(&cursor[st[e]], 1);
  e2[pos] = make_int2(ed[e], __float_as_int(w[e]));
}

// ---------------------------------------------------------------------------
// Gather from vertex-major pvm: per edge read 96 B contiguous (2 lines).
// ---------------------------------------------------------------------------
__global__ __launch_bounds__(256) void lap_gather_pvm_kernel(
    const int* __restrict__ rowstart, const int2* __restrict__ e2,
    const float* __restrict__ pvm, float* __restrict__ lap) {
  int v = blockIdx.x * blockDim.x + threadIdx.x;
  if (v >= V) return;
  int beg = rowstart[v];
  int end = rowstart[v + 1];
  float acc[24];
#pragma unroll
  for (int q = 0; q < 24; ++q) acc[q] = 0.f;
  for (int j = beg; j < end; ++j) {
    int2 ew = e2[j];
    float w = __int_as_float(ew.y);
    const float4* p = reinterpret_cast<const float4*>(pvm + (size_t)ew.x * 24);
#pragma unroll
    for (int q = 0; q < 6; ++q) {
      float4 t = p[q];
      acc[q * 4 + 0] += w * t.x;
      acc[q * 4 + 1] += w * t.y;
      acc[q * 4 + 2] += w * t.z;
      acc[q * 4 + 3] += w * t.w;
    }
  }
#pragma unroll
  for (int b = 0; b < B; ++b) {
    size_t o = ((size_t)b * V + v) * 3;
    lap[o + 0] = acc[b * 3 + 0];
    lap[o + 1] = acc[b * 3 + 1];
    lap[o + 2] = acc[b * 3 + 2];
  }
}

// Tier-B gather: from batch-major posed (= out) if ws can't hold pvm.
__global__ __launch_bounds__(256) void lap_gather_bm_kernel(
    const int* __restrict__ rowstart, const int2* __restrict__ e2,
    const float* __restrict__ posed, float* __restrict__ lap) {
  int v = blockIdx.x * blockDim.x + threadIdx.x;
  if (v >= V) return;
  int beg = rowstart[v];
  int end = rowstart[v + 1];
  float acc[B][3];
#pragma unroll
  for (int b = 0; b < B; ++b) { acc[b][0] = 0.f; acc[b][1] = 0.f; acc[b][2] = 0.f; }
  for (int j = beg; j < end; ++j) {
    int2 ew = e2[j];
    float w = __int_as_float(ew.y);
    const float* p = posed + (size_t)ew.x * 3;
#pragma unroll
    for (int b = 0; b < B; ++b) {
      const float* pb = p + (size_t)b * V * 3;
      acc[b][0] += w * pb[0];
      acc[b][1] += w * pb[1];
      acc[b][2] += w * pb[2];
    }
  }
#pragma unroll
  for (int b = 0; b < B; ++b) {
    size_t o = ((size_t)b * V + v) * 3;
    lap[o + 0] = acc[b][0];
    lap[o + 1] = acc[b][1];
    lap[o + 2] = acc[b][2];
  }
}

// Tier-C fallback: per-edge atomic scatter.
__global__ __launch_bounds__(256) void lap_atomic_kernel(
    const float* __restrict__ lapw, const int* __restrict__ st,
    const int* __restrict__ ed, const float* __restrict__ posed,
    float* __restrict__ lap) {
  int e = blockIdx.x * blockDim.x + threadIdx.x;
  if (e >= E) return;
  float w = lapw[e];
  int s = st[e];
  int d = ed[e];
#pragma unroll
  for (int b = 0; b < B; ++b) {
    size_t pb = ((size_t)b * V + d) * 3;
    size_t ob = ((size_t)b * V + s) * 3;
    atomicAdd(&lap[ob + 0], w * posed[pb + 0]);
    atomicAdd(&lap[ob + 1], w * posed[pb + 1]);
    atomicAdd(&lap[ob + 2], w * posed[pb + 2]);
  }
}

extern "C" void kernel_launch(void* const* d_in, const int* in_sizes, int n_in,
                              void* d_out, int out_size, void* d_ws, size_t ws_size,
                              hipStream_t stream) {
  const float* tv    = (const float*)d_in[0];
  const float* jquat = (const float*)d_in[1];
  const float* jtran = (const float*)d_in[2];
  const float* sw    = (const float*)d_in[3];
  const float* npos  = (const float*)d_in[4];
  const float* nquat = (const float*)d_in[5];
  const float* ntran = (const float*)d_in[6];
  const float* lw    = (const float*)d_in[7];
  const float* lapw  = (const float*)d_in[8];
  const int*   sidx  = (const int*)d_in[9];
  const int*   lidx  = (const int*)d_in[10];
  const int*   lst   = (const int*)d_in[11];
  const int*   led   = (const int*)d_in[12];
  float* out = (float*)d_out;
  float* lap = out + (size_t)B * V * 3;

  // workspace layout (e2 first so it is 8B-aligned; pvm 16B-aligned)
  float* jqd      = (float*)d_ws;                  // 4096 floats (16 KB)
  int2*  e2       = (int2*)(jqd + 4096);           // E int2   (14.68 MB)
  float* pvm      = (float*)(e2 + E);              // V*24 f   (25.17 MB)
  int*   cnt      = (int*)(pvm + (size_t)V * 24);  // V
  int*   rowstart = cnt + V;                       // V+1
  int*   cursor   = rowstart + V + 1;              // V
  int*   bsum     = cursor + V;                    // NBLK
  int*   boff     = bsum + NBLK;                   // NBLK
  size_t needA = (size_t)((char*)(boff + NBLK) - (char*)d_ws);
  size_t needB = needA - (size_t)V * 24 * sizeof(float);
  int tier = (ws_size >= needA) ? 0 : (ws_size >= needB) ? 1 : 2;

  if (tier == 1) {
    // shift CSR arrays down over the pvm hole
    cnt = (int*)(e2 + E);
    rowstart = cnt + V;
    cursor = rowstart + V + 1;
    bsum = cursor + V;
    boff = bsum + NBLK;
  }

  jqd_kernel<<<(B * J + 255) / 256, 256, 0, stream>>>(jquat, jtran, jqd);
  posed_kernel<<<V / 256, 256, 0, stream>>>(tv, sw, npos, nquat, ntran, lw,
                                            sidx, lidx, jqd, out, pvm, tier);
  if (tier <= 1) {
    hipMemsetAsync(cnt, 0, (size_t)V * sizeof(int), stream);
    hist_kernel<<<E / 256, 256, 0, stream>>>(lst, cnt);
    scan1_kernel<<<NBLK, 256, 0, stream>>>(cnt, rowstart, bsum);
    scan2_kernel<<<1, NBLK, 0, stream>>>(bsum, boff);
    scan3_kernel<<<NBLK, 256, 0, stream>>>(rowstart, boff, cursor);
    scatter_kernel<<<E / 256, 256, 0, stream>>>(lst, led, lapw, cursor, e2);
    if (tier == 0) {
      lap_gather_pvm_kernel<<<V / 256, 256, 0, stream>>>(rowstart, e2, pvm, lap);
    } else {
      lap_gather_bm_kernel<<<V / 256, 256, 0, stream>>>(rowstart, e2, out, lap);
    }
  } else {
    lap_atomic_kernel<<<E / 256, 256, 0, stream>>>(lapw, lst, led, out, lap);
  }
}

// Round 4
// 320.504 us; speedup vs baseline: 7.0593x; 1.2041x over previous
//
#include <hip/hip_runtime.h>
#include <hip/hip_bf16.h>
#include <math.h>

// Problem constants (fixed by the reference setup)
constexpr int B = 8;
constexpr int V = 262144;
constexpr int J = 64;
constexpr int K = 4;
constexpr int G = 2048;
constexpr int L = 8;
constexpr int E = 1835008;
constexpr float EPS = 1e-8f;
constexpr int NBLK = V / 256;   // 1024 scan blocks
constexpr int NBKT = 8;         // XCD buckets
constexpr int VPB = V / NBKT;   // 32768 keys per bucket
constexpr int BKT_GRID = 8192;  // blocks for bucketed kernels

__device__ inline unsigned bf16bits(float x) {
  unsigned u = __float_as_uint(x);
  return (u + 0x7fffu + ((u >> 16) & 1u)) >> 16;  // round-to-nearest-even
}

// ---------------------------------------------------------------------------
// Kernel 0: per (b,j) normalized joint quat + dual part jd = 0.5*qmul((0,t),q)
// ---------------------------------------------------------------------------
__global__ __launch_bounds__(256) void jqd_kernel(
    const float* __restrict__ jquat, const float* __restrict__ jtrans,
    float* __restrict__ ws) {
  int i = blockIdx.x * blockDim.x + threadIdx.x;
  if (i >= B * J) return;
  float qw = jquat[i * 4 + 0];
  float qx = jquat[i * 4 + 1];
  float qy = jquat[i * 4 + 2];
  float qz = jquat[i * 4 + 3];
  float inv = 1.0f / (sqrtf(qw * qw + qx * qx + qy * qy + qz * qz) + EPS);
  qw *= inv; qx *= inv; qy *= inv; qz *= inv;
  float tx = jtrans[i * 3 + 0];
  float ty = jtrans[i * 3 + 1];
  float tz = jtrans[i * 3 + 2];
  float dw = -0.5f * (tx * qx + ty * qy + tz * qz);
  float dx = 0.5f * (qw * tx + (ty * qz - tz * qy));
  float dy = 0.5f * (qw * ty + (tz * qx - tx * qz));
  float dz = 0.5f * (qw * tz + (tx * qy - ty * qx));
  float* o = ws + (size_t)i * 8;
  o[0] = qw; o[1] = qx; o[2] = qy; o[3] = qz;
  o[4] = dw; o[5] = dx; o[6] = dy; o[7] = dz;
}

// ---------------------------------------------------------------------------
// Kernel 1: one thread per vertex, loop over batches. Writes posed (out[0])
// and optionally a vertex-major bf16 copy pvm16[v]: 24 bf16 in a 64 B block.
// mode: 0 = write pvm16, 1 = no pvm, 2 = no pvm + zero lap (atomic fallback)
// ---------------------------------------------------------------------------
__global__ __launch_bounds__(256) void posed_kernel(
    const float* __restrict__ tv, const float* __restrict__ sw_in,
    const float* __restrict__ npos, const float* __restrict__ nquat,
    const float* __restrict__ ntrans, const float* __restrict__ lw_in,
    const int* __restrict__ sidx, const int* __restrict__ lidx,
    const float* __restrict__ jqd, float* __restrict__ out,
    unsigned* __restrict__ pvm16, int mode) {
  int v = blockIdx.x * blockDim.x + threadIdx.x;
  if (v >= V) return;

  float px = tv[(size_t)v * 3 + 0];
  float py = tv[(size_t)v * 3 + 1];
  float pz = tv[(size_t)v * 3 + 2];

  int4 si = *reinterpret_cast<const int4*>(sidx + (size_t)v * 4);
  float4 swv = *reinterpret_cast<const float4*>(sw_in + (size_t)v * 4);
  int4 li0 = *reinterpret_cast<const int4*>(lidx + (size_t)v * 8);
  int4 li1 = *reinterpret_cast<const int4*>(lidx + (size_t)v * 8 + 4);
  float4 lw0 = *reinterpret_cast<const float4*>(lw_in + (size_t)v * 8);
  float4 lw1 = *reinterpret_cast<const float4*>(lw_in + (size_t)v * 8 + 4);

  float sinv = 1.0f / (swv.x + swv.y + swv.z + swv.w + EPS);
  float swn[K] = {swv.x * sinv, swv.y * sinv, swv.z * sinv, swv.w * sinv};
  int sj[K] = {si.x, si.y, si.z, si.w};

  float linv =
      1.0f / (lw0.x + lw0.y + lw0.z + lw0.w + lw1.x + lw1.y + lw1.z + lw1.w + EPS);
  float lwn[L] = {lw0.x * linv, lw0.y * linv, lw0.z * linv, lw0.w * linv,
                  lw1.x * linv, lw1.y * linv, lw1.z * linv, lw1.w * linv};
  int gi[L] = {li0.x, li0.y, li0.z, li0.w, li1.x, li1.y, li1.z, li1.w};

  float lx[L], ly[L], lz[L];
  float bx = 0.f, by = 0.f, bz = 0.f;
#pragma unroll
  for (int l = 0; l < L; ++l) {
    float gx = npos[(size_t)gi[l] * 3 + 0];
    float gy = npos[(size_t)gi[l] * 3 + 1];
    float gz = npos[(size_t)gi[l] * 3 + 2];
    lx[l] = px - gx; ly[l] = py - gy; lz[l] = pz - gz;
    bx += lwn[l] * gx; by += lwn[l] * gy; bz += lwn[l] * gz;
  }

  constexpr size_t LAPOFF = (size_t)B * V * 3;
  float pv[24];

  for (int b = 0; b < B; ++b) {
    const float* nq_b = nquat + (size_t)b * G * 4;
    const float* nt_b = ntrans + (size_t)b * G * 3;

    float ex = bx, ey = by, ez = bz;
#pragma unroll
    for (int l = 0; l < L; ++l) {
      float4 q = *reinterpret_cast<const float4*>(nq_b + (size_t)gi[l] * 4);
      float qw = q.x, qx = q.y, qy = q.z, qz = q.w;
      float inv = 1.0f / (sqrtf(qw * qw + qx * qx + qy * qy + qz * qz) + EPS);
      qw *= inv; qx *= inv; qy *= inv; qz *= inv;
      float ux = lx[l], uy = ly[l], uz = lz[l];
      float cx = qy * uz - qz * uy + qw * ux;
      float cy = qz * ux - qx * uz + qw * uy;
      float cz = qx * uy - qy * ux + qw * uz;
      float rx = ux + 2.0f * (qy * cz - qz * cy);
      float ry = uy + 2.0f * (qz * cx - qx * cz);
      float rz = uz + 2.0f * (qx * cy - qy * cx);
      ex += lwn[l] * (rx + nt_b[(size_t)gi[l] * 3 + 0]);
      ey += lwn[l] * (ry + nt_b[(size_t)gi[l] * 3 + 1]);
      ez += lwn[l] * (rz + nt_b[(size_t)gi[l] * 3 + 2]);
    }

    float rbw = 0.f, rbx = 0.f, rby = 0.f, rbz = 0.f;
    float dbw = 0.f, dbx = 0.f, dby = 0.f, dbz = 0.f;
    float r0w = 0.f, r0x = 0.f, r0y = 0.f, r0z = 0.f;
#pragma unroll
    for (int k = 0; k < K; ++k) {
      const float* eptr = jqd + ((size_t)b * J + sj[k]) * 8;
      float4 qf = *reinterpret_cast<const float4*>(eptr);
      float4 df = *reinterpret_cast<const float4*>(eptr + 4);
      float qw = qf.x, qx = qf.y, qy = qf.z, qz = qf.w;
      if (k == 0) { r0w = qw; r0x = qx; r0y = qy; r0z = qz; }
      float dotr = qw * r0w + qx * r0x + qy * r0y + qz * r0z;
      float s = (dotr >= 0.0f) ? swn[k] : -swn[k];
      rbw += s * qw; rbx += s * qx; rby += s * qy; rbz += s * qz;
      dbw += s * df.x; dbx += s * df.y; dby += s * df.z; dbz += s * df.w;
    }
    float ninv = 1.0f / (sqrtf(rbw * rbw + rbx * rbx + rby * rby + rbz * rbz) + EPS);
    rbw *= ninv; rbx *= ninv; rby *= ninv; rbz *= ninv;
    dbw *= ninv; dbx *= ninv; dby *= ninv; dbz *= ninv;

    float txx = 2.0f * (rbw * dbx - dbw * rbx + (rby * dbz - rbz * dby));
    float tyy = 2.0f * (rbw * dby - dbw * rby + (rbz * dbx - rbx * dbz));
    float tzz = 2.0f * (rbw * dbz - dbw * rbz + (rbx * dby - rby * dbx));

    float cx = rby * ez - rbz * ey + rbw * ex;
    float cy = rbz * ex - rbx * ez + rbw * ey;
    float cz = rbx * ey - rby * ex + rbw * ez;
    float ox = ex + 2.0f * (rby * cz - rbz * cy) + txx;
    float oy = ey + 2.0f * (rbz * cx - rbx * cz) + tyy;
    float oz = ez + 2.0f * (rbx * cy - rby * cx) + tzz;

    size_t o = ((size_t)b * V + v) * 3;
    out[o + 0] = ox; out[o + 1] = oy; out[o + 2] = oz;
    pv[b * 3 + 0] = ox; pv[b * 3 + 1] = oy; pv[b * 3 + 2] = oz;
    if (mode == 2) {
      out[LAPOFF + o + 0] = 0.f;
      out[LAPOFF + o + 1] = 0.f;
      out[LAPOFF + o + 2] = 0.f;
    }
  }

  if (mode == 0) {
    // pack 24 floats -> 12 uints (24 bf16) in a 64 B-aligned block
    unsigned pk[12];
#pragma unroll
    for (int i = 0; i < 12; ++i)
      pk[i] = bf16bits(pv[2 * i]) | (bf16bits(pv[2 * i + 1]) << 16);
    uint4* dst = reinterpret_cast<uint4*>(pvm16 + (size_t)v * 16);
    dst[0] = make_uint4(pk[0], pk[1], pk[2], pk[3]);
    dst[1] = make_uint4(pk[4], pk[5], pk[6], pk[7]);
    dst[2] = make_uint4(pk[8], pk[9], pk[10], pk[11]);
  }
}

// ---------------------------------------------------------------------------
// CSR build: XCD-bucketed histogram -> scan -> XCD-bucketed scatter.
// Blocks with (blockIdx&7)==p handle keys in [p*VPB,(p+1)*VPB): with the
// round-robin block->XCD mapping all partial-line writes of a bucket come
// from ONE XCD and merge in its private L2.
// ---------------------------------------------------------------------------
__global__ __launch_bounds__(256) void hist_bucketed_kernel(
    const int* __restrict__ st, int* __restrict__ cnt) {
  int p = blockIdx.x & (NBKT - 1);
  int lo = p * VPB, hi = lo + VPB;
  int stride = (gridDim.x / NBKT) * 256;
  for (int e = (blockIdx.x / NBKT) * 256 + (int)threadIdx.x; e < E; e += stride) {
    int s = st[e];
    if (s >= lo && s < hi) atomicAdd(&cnt[s], 1);
  }
}

__global__ __launch_bounds__(256) void scan1_kernel(const int* __restrict__ cnt,
                                                    int* __restrict__ excl,
                                                    int* __restrict__ bsum) {
  __shared__ int s[256];
  int t = threadIdx.x;
  int i = blockIdx.x * 256 + t;
  int x = cnt[i];
  s[t] = x;
  __syncthreads();
  for (int off = 1; off < 256; off <<= 1) {
    int val = (t >= off) ? s[t - off] : 0;
    __syncthreads();
    s[t] += val;
    __syncthreads();
  }
  excl[i] = s[t] - x;
  if (t == 255) bsum[blockIdx.x] = s[t];
}

__global__ __launch_bounds__(1024) void scan2_kernel(const int* __restrict__ bsum,
                                                     int* __restrict__ boff) {
  __shared__ int s[NBLK];
  int t = threadIdx.x;
  int x = bsum[t];
  s[t] = x;
  __syncthreads();
  for (int off = 1; off < NBLK; off <<= 1) {
    int val = (t >= off) ? s[t - off] : 0;
    __syncthreads();
    s[t] += val;
    __syncthreads();
  }
  boff[t] = s[t] - x;
}

__global__ __launch_bounds__(256) void scan3_kernel(int* __restrict__ excl,
                                                    const int* __restrict__ boff,
                                                    int* __restrict__ cursor) {
  int i = blockIdx.x * 256 + threadIdx.x;
  int r = excl[i] + boff[blockIdx.x];
  excl[i] = r;
  cursor[i] = r;
  if (i == 0) excl[V] = E;
}

__global__ __launch_bounds__(256) void scatter_bucketed_kernel(
    const int* __restrict__ st, const int* __restrict__ ed,
    const float* __restrict__ w, int* __restrict__ cursor,
    int2* __restrict__ e2) {
  int p = blockIdx.x & (NBKT - 1);
  int lo = p * VPB, hi = lo + VPB;
  int stride = (gridDim.x / NBKT) * 256;
  for (int e = (blockIdx.x / NBKT) * 256 + (int)threadIdx.x; e < E; e += stride) {
    int s = st[e];
    if (s >= lo && s < hi) {
      int pos = atomicAdd(&cursor[s], 1);
      e2[pos] = make_int2(ed[e], __float_as_int(w[e]));
    }
  }
}

// ---------------------------------------------------------------------------
// Gather from bf16 vertex-major pvm16: one 64 B line per edge.
// ---------------------------------------------------------------------------
__global__ __launch_bounds__(256) void lap_gather_pvm16_kernel(
    const int* __restrict__ rowstart, const int2* __restrict__ e2,
    const unsigned* __restrict__ pvm16, float* __restrict__ lap) {
  int v = blockIdx.x * blockDim.x + threadIdx.x;
  if (v >= V) return;
  int beg = rowstart[v];
  int end = rowstart[v + 1];
  float acc[24];
#pragma unroll
  for (int q = 0; q < 24; ++q) acc[q] = 0.f;
  for (int j = beg; j < end; ++j) {
    int2 ew = e2[j];
    float w = __int_as_float(ew.y);
    const uint4* p = reinterpret_cast<const uint4*>(pvm16 + (size_t)ew.x * 16);
    uint4 a = p[0], bq = p[1], c = p[2];
    unsigned u[12] = {a.x, a.y, a.z, a.w, bq.x, bq.y, bq.z, bq.w,
                      c.x, c.y, c.z, c.w};
#pragma unroll
    for (int i = 0; i < 12; ++i) {
      acc[2 * i + 0] += w * __uint_as_float(u[i] << 16);
      acc[2 * i + 1] += w * __uint_as_float(u[i] & 0xffff0000u);
    }
  }
#pragma unroll
  for (int b = 0; b < B; ++b) {
    size_t o = ((size_t)b * V + v) * 3;
    lap[o + 0] = acc[b * 3 + 0];
    lap[o + 1] = acc[b * 3 + 1];
    lap[o + 2] = acc[b * 3 + 2];
  }
}

// Tier-B gather: from batch-major posed (= out) if ws can't hold pvm16.
__global__ __launch_bounds__(256) void lap_gather_bm_kernel(
    const int* __restrict__ rowstart, const int2* __restrict__ e2,
    const float* __restrict__ posed, float* __restrict__ lap) {
  int v = blockIdx.x * blockDim.x + threadIdx.x;
  if (v >= V) return;
  int beg = rowstart[v];
  int end = rowstart[v + 1];
  float acc[B][3];
#pragma unroll
  for (int b = 0; b < B; ++b) { acc[b][0] = 0.f; acc[b][1] = 0.f; acc[b][2] = 0.f; }
  for (int j = beg; j < end; ++j) {
    int2 ew = e2[j];
    float w = __int_as_float(ew.y);
    const float* p = posed + (size_t)ew.x * 3;
#pragma unroll
    for (int b = 0; b < B; ++b) {
      const float* pb = p + (size_t)b * V * 3;
      acc[b][0] += w * pb[0];
      acc[b][1] += w * pb[1];
      acc[b][2] += w * pb[2];
    }
  }
#pragma unroll
  for (int b = 0; b < B; ++b) {
    size_t o = ((size_t)b * V + v) * 3;
    lap[o + 0] = acc[b][0];
    lap[o + 1] = acc[b][1];
    lap[o + 2] = acc[b][2];
  }
}

// Tier-C fallback: per-edge atomic scatter.
__global__ __launch_bounds__(256) void lap_atomic_kernel(
    const float* __restrict__ lapw, const int* __restrict__ st,
    const int* __restrict__ ed, const float* __restrict__ posed,
    float* __restrict__ lap) {
  int e = blockIdx.x * blockDim.x + threadIdx.x;
  if (e >= E) return;
  float w = lapw[e];
  int s = st[e];
  int d = ed[e];
#pragma unroll
  for (int b = 0; b < B; ++b) {
    size_t pb = ((size_t)b * V + d) * 3;
    size_t ob = ((size_t)b * V + s) * 3;
    atomicAdd(&lap[ob + 0], w * posed[pb + 0]);
    atomicAdd(&lap[ob + 1], w * posed[pb + 1]);
    atomicAdd(&lap[ob + 2], w * posed[pb + 2]);
  }
}

extern "C" void kernel_launch(void* const* d_in, const int* in_sizes, int n_in,
                              void* d_out, int out_size, void* d_ws, size_t ws_size,
                              hipStream_t stream) {
  const float* tv    = (const float*)d_in[0];
  const float* jquat = (const float*)d_in[1];
  const float* jtran = (const float*)d_in[2];
  const float* sw    = (const float*)d_in[3];
  const float* npos  = (const float*)d_in[4];
  const float* nquat = (const float*)d_in[5];
  const float* ntran = (const float*)d_in[6];
  const float* lw    = (const float*)d_in[7];
  const float* lapw  = (const float*)d_in[8];
  const int*   sidx  = (const int*)d_in[9];
  const int*   lidx  = (const int*)d_in[10];
  const int*   lst   = (const int*)d_in[11];
  const int*   led   = (const int*)d_in[12];
  float* out = (float*)d_out;
  float* lap = out + (size_t)B * V * 3;

  // workspace layout
  float*    jqd      = (float*)d_ws;                    // 4096 floats (16 KB)
  int2*     e2       = (int2*)(jqd + 4096);             // E int2   (14.68 MB)
  unsigned* pvm16    = (unsigned*)(e2 + E);             // V*16 u32 (16.78 MB)
  int*      cnt      = (int*)(pvm16 + (size_t)V * 16);  // V
  int*      rowstart = cnt + V;                         // V+1
  int*      cursor   = rowstart + V + 1;                // V
  int*      bsum     = cursor + V;                      // NBLK
  int*      boff     = bsum + NBLK;                     // NBLK
  size_t needA = (size_t)((char*)(boff + NBLK) - (char*)d_ws);
  size_t needB = needA - (size_t)V * 16 * sizeof(unsigned);
  int tier = (ws_size >= needA) ? 0 : (ws_size >= needB) ? 1 : 2;

  if (tier == 1) {
    // shift CSR arrays down over the pvm16 hole
    cnt = (int*)(e2 + E);
    rowstart = cnt + V;
    cursor = rowstart + V + 1;
    bsum = cursor + V;
    boff = bsum + NBLK;
  }

  jqd_kernel<<<(B * J + 255) / 256, 256, 0, stream>>>(jquat, jtran, jqd);
  posed_kernel<<<V / 256, 256, 0, stream>>>(tv, sw, npos, nquat, ntran, lw,
                                            sidx, lidx, jqd, out, pvm16, tier);
  if (tier <= 1) {
    hipMemsetAsync(cnt, 0, (size_t)V * sizeof(int), stream);
    hist_bucketed_kernel<<<BKT_GRID, 256, 0, stream>>>(lst, cnt);
    scan1_kernel<<<NBLK, 256, 0, stream>>>(cnt, rowstart, bsum);
    scan2_kernel<<<1, NBLK, 0, stream>>>(bsum, boff);
    scan3_kernel<<<NBLK, 256, 0, stream>>>(rowstart, boff, cursor);
    scatter_bucketed_kernel<<<BKT_GRID, 256, 0, stream>>>(lst, led, lapw,
                                                          cursor, e2);
    if (tier == 0) {
      lap_gather_pvm16_kernel<<<V / 256, 256, 0, stream>>>(rowstart, e2, pvm16,
                                                           lap);
    } else {
      lap_gather_bm_kernel<<<V / 256, 256, 0, stream>>>(rowstart, e2, out, lap);
    }
  } else {
    lap_atomic_kernel<<<E / 256, 256, 0, stream>>>(lapw, lst, led, out, lap);
  }
}